// Round 9
// baseline (594.345 us; speedup 1.0000x reference)
//
#include <hip/hip_runtime.h>

#define NN 100000
#define EE 1600000
#define GG 2048
#define EPSB 1e-5f
#define MP 100096        // NN padded to multiple of 128
#define MBLK (MP / 128)  // 782
#define NB 782           // buckets of 128 dest nodes
#define CAP 2560         // bucket entry capacity (mean 2046, sd ~45)
#define CAPP 3584        // per-bucket srcs region (CAP + 128*8 pad room)

typedef unsigned short u16;
typedef __attribute__((ext_vector_type(8))) short short8;
typedef __attribute__((ext_vector_type(4))) float f32x4;

struct alignas(4)  u16x2 { u16 v[2]; };
struct alignas(8)  u16x4 { u16 v[4]; };
struct alignas(16) u16x8 { u16 v[8]; };

__device__ __forceinline__ float b2f(u16 u) { return __uint_as_float(((unsigned)u) << 16); }
__device__ __forceinline__ u16 f2b(float f) {
    unsigned u = __float_as_uint(f);
    return (u16)((u + 0x7FFF + ((u >> 16) & 1)) >> 16);
}
__device__ __forceinline__ void gload16(const void* g, void* l) {
    __builtin_amdgcn_global_load_lds((const __attribute__((address_space(1))) void*)g,
                                     (__attribute__((address_space(3))) void*)l, 16, 0, 0);
}

// ---------------- init: all zero-fills in one dispatch ----------------
// u32 ranges: bcur[NB*16] | statsAll[1280] | dinv[NN]=0 | bufA pad128 | bufA pad256

#define ZB0 (NB * 16)
#define ZB1 (ZB0 + 1280)
#define ZB2 (ZB1 + 1)
#define ZB3 (ZB2 + (MP - NN) * 64)    // (MP-NN)*128 u16 = *64 u32
#define ZB4 (ZB3 + (MP - NN) * 128)   // (MP-NN)*256 u16 = *128 u32

__global__ void init_kernel(unsigned* __restrict__ bcur, unsigned* __restrict__ statsAll,
                            unsigned* __restrict__ dinvNN, unsigned* __restrict__ padA128,
                            unsigned* __restrict__ padA256) {
    int i = blockIdx.x * 256 + threadIdx.x;
    if (i < ZB0) bcur[i] = 0u;
    else if (i < ZB1) statsAll[i - ZB0] = 0u;
    else if (i < ZB2) dinvNN[0] = 0u;
    else if (i < ZB3) padA128[i - ZB2] = 0u;
    else if (i < ZB4) padA256[i - ZB3] = 0u;
}

// ---------------- CSR build (bucketed, fixed-stride regions) ----------------

__global__ void bucketA_kernel(const int* __restrict__ row, const int* __restrict__ col,
                               int* __restrict__ bcur, unsigned* __restrict__ bkt) {
    int e = blockIdx.x * 256 + threadIdx.x;
    if (e < EE) {
        int c = col[e], r = row[e];
        int b = c >> 7;
        int p = atomicAdd(&bcur[b * 16], 1);
        if (p < CAP) bkt[(size_t)b * CAP + p] = ((unsigned)r << 7) | (unsigned)(c & 127);
    }
}

// count + local padded scan + dinv + begs/ends + LDS scatter + per-node SOURCE SORT + pad
__global__ void bucketBC_kernel(const unsigned* __restrict__ bkt, const int* __restrict__ bcur,
                                int* __restrict__ begs, int* __restrict__ ends,
                                float* __restrict__ dinv, int* __restrict__ srcs) {
    int b = blockIdx.x, t = threadIdx.x;   // 256 threads
    __shared__ int lcnt[128];
    __shared__ int sp[128];
    __shared__ int cur[128];
    __shared__ int sarr[CAPP];             // 14KB staging for the whole bucket
    if (t < 128) lcnt[t] = 0;
    __syncthreads();
    int tot = bcur[b * 16];
    if (tot > CAP) tot = CAP;
    const unsigned* B = bkt + (size_t)b * CAP;
    for (int i = t; i < tot; i += 256) atomicAdd(&lcnt[(int)(B[i] & 127u)], 1);
    __syncthreads();
    int n0 = b << 7;
    int pc = 0, rc = 0;
    if (t < 128) {
        rc = lcnt[t];
        if (n0 + t < NN) dinv[n0 + t] = rsqrtf((float)(rc + 1));
        pc = (rc + 7) & ~7;
        sp[t] = pc;
    }
    __syncthreads();
    for (int o = 1; o < 128; o <<= 1) {
        int u = (t >= o && t < 128) ? sp[t - o] : 0;
        __syncthreads();
        if (t < 128) sp[t] += u;
        __syncthreads();
    }
    int stl = 0;
    if (t < 128) {
        stl = sp[t] - pc;          // local (in-bucket) start
        cur[t] = stl;
    }
    __syncthreads();
    for (int i = t; i < tot; i += 256) {
        unsigned v = B[i];
        int p = atomicAdd(&cur[(int)(v & 127u)], 1);
        sarr[p] = (int)(v >> 7);
    }
    __syncthreads();
    if (t < 128) {
        // dummy-pad to multiple of 8 (dinv[NN]=0)
        for (int i = stl + rc; i < stl + pc; ++i) sarr[i] = NN;
        // insertion sort by source: correlated sweep across concurrent nodes -> L2 locality
        for (int i = stl + 1; i < stl + rc; ++i) {
            int key = sarr[i];
            int j = i - 1;
            while (j >= stl && sarr[j] > key) { sarr[j + 1] = sarr[j]; --j; }
            sarr[j + 1] = key;
        }
    }
    __syncthreads();
    int base = b * CAPP;
    int total = sp[127];
    for (int i = t; i < total; i += 256) srcs[base + i] = sarr[i];
    if (t < 128 && n0 + t < NN) { begs[n0 + t] = base + stl; ends[n0 + t] = base + stl + pc; }
}

// ---------------- casts (x + all 3 weights, one dispatch) ----------------

__global__ void xwcast_kernel(const float* __restrict__ x, u16* __restrict__ xb,
                              const float* __restrict__ W1, const float* __restrict__ W2,
                              const float* __restrict__ W3, u16* __restrict__ Wt1,
                              u16* __restrict__ Wt2, u16* __restrict__ Wt3) {
    int idx = blockIdx.x * 256 + threadIdx.x;
    if (idx < NN * 32) {
        float4 v = ((const float4*)x)[idx];
        u16x4 o = {{f2b(v.x), f2b(v.y), f2b(v.z), f2b(v.w)}};
        ((u16x4*)xb)[idx] = o;
        return;
    }
    int j = idx - NN * 32;
    if (j < 32768) {                  // Wt1[n*128+k] = W1[k*256+n]
        int n = j >> 7, k = j & 127;
        Wt1[j] = f2b(W1[k * 256 + n]);
    } else if (j < 98304) {           // Wt2[n*256+k] = W2[k*256+n]
        int jj = j - 32768;
        int n = jj >> 8, k = jj & 255;
        Wt2[jj] = f2b(W2[k * 256 + n]);
    } else if (j < 131072) {          // Wt3[n*256+k] = W3[k*128+n]
        int jj = j - 98304;
        int n = jj >> 8, k = jj & 255;
        Wt3[jj] = f2b(W3[k * 128 + n]);
    }
}

// ---------------- aggregation (GROUP lanes per node; lists padded to x8) ----------------
// out[i] = dinv[i] * ( sum_e dinv[src_e]*f(X[src_e]) + dinv[i]*f(X[i]) ); f = id or relu(s*z+t)

template <int F, int GROUP, bool TR>
__global__ void agg_kernel(const u16* __restrict__ X, u16* __restrict__ out,
                           const int* __restrict__ begs, const int* __restrict__ ends,
                           const int* __restrict__ srcs, const float* __restrict__ dinv,
                           const float* __restrict__ sc, const float* __restrict__ shf) {
    constexpr int VE = F / GROUP;        // 4 for both (256/64, 128/32)
    constexpr int NPB = 256 / GROUP;     // nodes per block: 4 or 8
    int node = blockIdx.x * NPB + threadIdx.x / GROUP;
    if (node >= NN) return;
    int l = threadIdx.x & (GROUP - 1);
    int f0 = l * VE;
    float s_[VE], t_[VE];
    if (TR) {
#pragma unroll
        for (int j = 0; j < VE; ++j) { s_[j] = sc[f0 + j]; t_[j] = shf[f0 + j]; }
    }
    float acc[VE] = {};
    int beg = begs[node], end = ends[node];

    auto fetch = [&](int s, u16* u) {
        if (VE == 4) *(u16x4*)u = *(const u16x4*)(X + (size_t)s * F + f0);
        else         *(u16x2*)u = *(const u16x2*)(X + (size_t)s * F + f0);
    };
    auto accum = [&](const u16* u, float w) {
#pragma unroll
        for (int j = 0; j < VE; ++j) {
            float v = b2f(u[j]);
            if (TR) v = fmaxf(fmaf(s_[j], v, t_[j]), 0.f);
            acc[j] = fmaf(w, v, acc[j]);
        }
    };

    for (int e0 = beg; e0 < end; e0 += GROUP) {
        int take = end - e0;
        if (take > GROUP) take = GROUP;   // always a multiple of 8
        int sv = (l < take) ? srcs[e0 + l] : NN;
        float wv = dinv[sv];
        for (int j = 0; j < take; j += 8) {
            int s[8];
            float w[8];
            u16 u[8][VE];
#pragma unroll
            for (int q = 0; q < 8; ++q) {
                s[q] = __shfl(sv, j + q, GROUP);
                w[q] = __shfl(wv, j + q, GROUP);
            }
#pragma unroll
            for (int q = 0; q < 8; ++q) fetch(s[q], u[q]);
#pragma unroll
            for (int q = 0; q < 8; ++q) accum(u[q], w[q]);
        }
    }
    float di = dinv[node];
    u16 us[VE];
    fetch(node, us);
    accum(us, di);
    if (VE == 4) {
        u16x4 o = {{f2b(di * acc[0]), f2b(di * acc[1]), f2b(di * acc[2]), f2b(di * acc[3])}};
        *(u16x4*)(out + (size_t)node * F + f0) = o;
    } else {
        u16x2 o = {{f2b(di * acc[0]), f2b(di * acc[1])}};
        *(u16x2*)(out + (size_t)node * F + f0) = o;
    }
}

// ---------------- MFMA GEMM: C[MP,Nout](bf16) = f(A[MP,Kdim]) @ Wt[Nout,Kdim]^T ----------------
// STATS: LDS-reduce column (sum,sumsq) partials, then 256 atomicAdds into gstats[2*Nout].

template <bool STATS, bool FUSEA>
__global__ __launch_bounds__(256) void gemm_kernel(const u16* __restrict__ A,
                                                   const u16* __restrict__ Wt,
                                                   u16* __restrict__ C,
                                                   int Kdim, int Nout,
                                                   float* __restrict__ gstats,
                                                   const float* __restrict__ sc,
                                                   const float* __restrict__ shf) {
    __shared__ u16 As[128 * 64];
    __shared__ u16 Bs[128 * 64];
    __shared__ float sbuf[2][128];
    const int tid = threadIdx.x;
    const int w = tid >> 6, l = tid & 63;
    const int row0 = blockIdx.x * 128;
    const int col0 = blockIdx.y * 128;
    const int srow = w * 32 + (l >> 3);
    const int skel = (l & 7) * 8;
    const u16* Asrc = A + (size_t)(row0 + srow) * Kdim + skel;
    const u16* Bsrc = Wt + (size_t)(col0 + srow) * Kdim + skel;
    u16* AsBase = &As[w * 2048];
    u16* BsBase = &Bs[w * 2048];
    const int wr = (w >> 1) * 64, wc = (w & 1) * 64;
    f32x4 acc[4][4] = {};
    if (STATS && tid < 128) { sbuf[0][tid] = 0.f; sbuf[1][tid] = 0.f; }

    for (int k0 = 0; k0 < Kdim; k0 += 64) {
        if (FUSEA) {
            float4 sa0 = *(const float4*)&sc[k0 + skel];
            float4 sa1 = *(const float4*)&sc[k0 + skel + 4];
            float4 ta0 = *(const float4*)&shf[k0 + skel];
            float4 ta1 = *(const float4*)&shf[k0 + skel + 4];
            float sA[8] = {sa0.x, sa0.y, sa0.z, sa0.w, sa1.x, sa1.y, sa1.z, sa1.w};
            float tA[8] = {ta0.x, ta0.y, ta0.z, ta0.w, ta1.x, ta1.y, ta1.z, ta1.w};
#pragma unroll
            for (int j = 0; j < 4; ++j) {
                u16x8 av = *(const u16x8*)(Asrc + (size_t)(j * 8) * Kdim + k0);
                u16x8 o;
#pragma unroll
                for (int i = 0; i < 8; ++i)
                    o.v[i] = f2b(fmaxf(fmaf(sA[i], b2f(av.v[i]), tA[i]), 0.f));
                *(u16x8*)&As[(w * 32 + j * 8 + (l >> 3)) * 64 + skel] = o;
            }
        } else {
#pragma unroll
            for (int j = 0; j < 4; ++j)
                gload16(Asrc + (size_t)(j * 8) * Kdim + k0, AsBase + j * 512);
        }
#pragma unroll
        for (int j = 0; j < 4; ++j)
            gload16(Bsrc + (size_t)(j * 8) * Kdim + k0, BsBase + j * 512);
        __syncthreads();
#pragma unroll
        for (int ks = 0; ks < 2; ++ks) {
            short8 a[4], b[4];
#pragma unroll
            for (int mi = 0; mi < 4; ++mi)
                a[mi] = *(const short8*)&As[(wr + mi * 16 + (l & 15)) * 64 + ks * 32 + (l >> 4) * 8];
#pragma unroll
            for (int ni = 0; ni < 4; ++ni)
                b[ni] = *(const short8*)&Bs[(wc + ni * 16 + (l & 15)) * 64 + ks * 32 + (l >> 4) * 8];
#pragma unroll
            for (int mi = 0; mi < 4; ++mi)
#pragma unroll
                for (int ni = 0; ni < 4; ++ni)
                    acc[mi][ni] = __builtin_amdgcn_mfma_f32_16x16x32_bf16(a[mi], b[ni], acc[mi][ni], 0, 0, 0);
        }
        __syncthreads();
    }
    const int cr = (l >> 4) * 4, cc = l & 15;
#pragma unroll
    for (int mi = 0; mi < 4; ++mi) {
#pragma unroll
        for (int j = 0; j < 4; ++j) {
            int r = row0 + wr + mi * 16 + cr + j;
#pragma unroll
            for (int ni = 0; ni < 4; ++ni)
                C[(size_t)r * Nout + col0 + wc + ni * 16 + cc] = f2b(acc[mi][ni][j]);
        }
    }
    if (STATS) {
#pragma unroll
        for (int ni = 0; ni < 4; ++ni) {
            float s = 0.f, q = 0.f;
#pragma unroll
            for (int mi = 0; mi < 4; ++mi)
#pragma unroll
                for (int jj = 0; jj < 4; ++jj) {
                    float v = acc[mi][ni][jj];
                    s += v;
                    q += v * v;
                }
            s += __shfl_xor(s, 16); s += __shfl_xor(s, 32);
            q += __shfl_xor(q, 16); q += __shfl_xor(q, 32);
            if (l < 16) {
                atomicAdd(&sbuf[0][wc + ni * 16 + l], s);
                atomicAdd(&sbuf[1][wc + ni * 16 + l], q);
            }
        }
        __syncthreads();
        if (tid < 128) {
            atomicAdd(&gstats[col0 + tid], sbuf[0][tid]);
            atomicAdd(&gstats[Nout + col0 + tid], sbuf[1][tid]);
        }
    }
}

// ---------------- finalize (tiny): sums[2F] -> scale/shift ----------------

__global__ void finalize_kernel(const float* __restrict__ sums, int F,
                                const float* __restrict__ g, const float* __restrict__ be,
                                float* __restrict__ sc, float* __restrict__ shf) {
    int f = threadIdx.x;
    if (f < F) {
        float m = sums[f] * (1.f / NN);
        float v = sums[F + f] * (1.f / NN) - m * m;
        float s = g[f] * rsqrtf(v + EPSB);
        sc[f] = s;
        shf[f] = be[f] - m * s;
    }
}

// ---------------- fused layer-3 stats + pool ----------------

__global__ void poolstats_kernel(const u16* __restrict__ Z, const int* __restrict__ batch,
                                 float* __restrict__ gsum, int* __restrict__ gcnt,
                                 float* __restrict__ sums) {
    int gph = blockIdx.x;
    int f = threadIdx.x;   // 128
    __shared__ int sb, se;
    if (f == 0) {
        int lo = 0, hi = NN;
        while (lo < hi) { int mid = (lo + hi) >> 1; if (batch[mid] < gph) lo = mid + 1; else hi = mid; }
        sb = lo;
        hi = NN;
        while (lo < hi) { int mid = (lo + hi) >> 1; if (batch[mid] < gph + 1) lo = mid + 1; else hi = mid; }
        se = lo;
    }
    __syncthreads();
    int beg = sb, end = se;
    float acc = 0.f, qq = 0.f;
    for (int r = beg; r < end; ++r) {
        float v = b2f(Z[(size_t)r * 128 + f]);
        acc += v;
        qq += v * v;
    }
    gsum[(size_t)gph * 128 + f] = acc;
    if (f == 0) gcnt[gph] = end - beg;
    atomicAdd(&sums[f], acc);
    atomicAdd(&sums[128 + f], qq);
}

// poolout with fused layer-3 finalize (recompute per thread from the tiny stats buffer)
__global__ void poolout_kernel(const float* __restrict__ gsum, const int* __restrict__ gcnt,
                               const float* __restrict__ sums,
                               const float* __restrict__ g, const float* __restrict__ be,
                               float* __restrict__ out) {
    int i = blockIdx.x * 256 + threadIdx.x;
    if (i < GG * 128) {
        int gr = i >> 7, f = i & 127;
        float m = sums[f] * (1.f / NN);
        float v = sums[128 + f] * (1.f / NN) - m * m;
        float scv = g[f] * rsqrtf(v + EPSB);
        float shv = be[f] - m * scv;
        int c = gcnt[gr];
        out[i] = (c > 0) ? fmaf(scv, gsum[i] / (float)c, shv) : 0.f;
    }
}

// ---------------- launch ----------------

extern "C" void kernel_launch(void* const* d_in, const int* in_sizes, int n_in,
                              void* d_out, int out_size, void* d_ws, size_t ws_size,
                              hipStream_t stream) {
    const float* x     = (const float*)d_in[0];
    const int*   row   = (const int*)d_in[1];
    const int*   col   = (const int*)d_in[2];
    const int*   batch = (const int*)d_in[3];
    const float* W1 = (const float*)d_in[4];
    const float* g1 = (const float*)d_in[6];
    const float* be1 = (const float*)d_in[7];
    const float* W2 = (const float*)d_in[8];
    const float* g2 = (const float*)d_in[10];
    const float* be2 = (const float*)d_in[11];
    const float* W3 = (const float*)d_in[12];
    const float* g3 = (const float*)d_in[14];
    const float* be3 = (const float*)d_in[15];
    float* out = (float*)d_out;

    char* ws = (char*)d_ws;
    size_t off = 0;
    auto alloc = [&](size_t bytes) { size_t o = off; off += (bytes + 255) & ~255ULL; return o; };
    u16*   bufA   = (u16*)  (ws + alloc((size_t)MP * 256 * 2));   // T1 / T2 / H3
    u16*   bufB   = (u16*)  (ws + alloc((size_t)MP * 256 * 2));   // Z1 / Z2
    u16*   xb     = (u16*)  (ws + alloc((size_t)MP * 128 * 2));   // x bf16, later Z3
    u16*   Wt1    = (u16*)  (ws + alloc(128 * 256 * 2));
    u16*   Wt2    = (u16*)  (ws + alloc(256 * 256 * 2));
    u16*   Wt3    = (u16*)  (ws + alloc(256 * 128 * 2));
    int*   begs   = (int*)  (ws + alloc((size_t)(NN + 16) * 4));
    int*   ends   = (int*)  (ws + alloc((size_t)(NN + 16) * 4));
    float* dinv   = (float*)(ws + alloc((size_t)(NN + 16) * 4));
    int*   srcs   = (int*)  (ws + alloc((size_t)NB * CAPP * 4));
    unsigned* bkt = (unsigned*)(ws + alloc((size_t)NB * CAP * 4));
    int*   bcur   = (int*)  (ws + alloc((size_t)NB * 16 * 4));
    float* statsAll = (float*)(ws + alloc(1280 * 4));   // l1[512] | l2[512] | p3[256]
    float* scbuf  = (float*)(ws + alloc(6 * 256 * 4));
    float* gsum   = (float*)(ws + alloc((size_t)GG * 128 * 4));
    int*   gcnt   = (int*)  (ws + alloc((size_t)GG * 4));

    // one init dispatch for all zero-fills (replay-safe)
    init_kernel<<<(ZB4 + 255) / 256, 256, 0, stream>>>(
        (unsigned*)bcur, (unsigned*)statsAll, (unsigned*)&dinv[NN],
        (unsigned*)(bufA + (size_t)NN * 128), (unsigned*)(bufA + (size_t)NN * 256));

    bucketA_kernel<<<(EE + 255) / 256, 256, 0, stream>>>(row, col, bcur, bkt);
    bucketBC_kernel<<<NB, 256, 0, stream>>>(bkt, bcur, begs, ends, dinv, srcs);

    xwcast_kernel<<<(NN * 32 + 131072 + 255) / 256, 256, 0, stream>>>(
        x, xb, W1, W2, W3, Wt1, Wt2, Wt3);

    // Layer 1: T1 = S@xb, Z1 = T1@W1 (stats via fused atomics)
    agg_kernel<128, 32, false><<<NN / 8, 256, 0, stream>>>(xb, bufA, begs, ends, srcs, dinv, nullptr, nullptr);
    gemm_kernel<true, false><<<dim3(MBLK, 2), 256, 0, stream>>>(bufA, Wt1, bufB, 128, 256, statsAll, nullptr, nullptr);
    finalize_kernel<<<1, 256, 0, stream>>>(statsAll, 256, g1, be1, scbuf + 0, scbuf + 256);

    // Layer 2: T2 = S@relu(bn1(Z1)) (BN fused in gather), Z2 = T2@W2 (stats via fused atomics)
    agg_kernel<256, 64, true><<<NN / 4, 256, 0, stream>>>(bufB, bufA, begs, ends, srcs, dinv, scbuf + 0, scbuf + 256);
    gemm_kernel<true, false><<<dim3(MBLK, 2), 256, 0, stream>>>(bufA, Wt2, bufB, 256, 256, statsAll + 512, nullptr, nullptr);
    finalize_kernel<<<1, 256, 0, stream>>>(statsAll + 512, 256, g2, be2, scbuf + 512, scbuf + 768);

    // Layer 3: H3 = relu(bn2(Z2))@W3 (BN fused in A-staging), Z3 = S@H3
    gemm_kernel<false, true><<<dim3(MBLK, 1), 256, 0, stream>>>(bufB, Wt3, bufA, 256, 128, nullptr, scbuf + 512, scbuf + 768);
    agg_kernel<128, 32, false><<<NN / 8, 256, 0, stream>>>(bufA, xb, begs, ends, srcs, dinv, nullptr, nullptr);
    poolstats_kernel<<<GG, 128, 0, stream>>>(xb, batch, gsum, gcnt, statsAll + 1024);
    poolout_kernel<<<(GG * 128 + 255) / 256, 256, 0, stream>>>(gsum, gcnt, statsAll + 1024, g3, be3, out);
}

// Round 10
// 557.948 us; speedup vs baseline: 1.0652x; 1.0652x over previous
//
#include <hip/hip_runtime.h>

#define NN 100000
#define EE 1600000
#define GG 2048
#define EPSB 1e-5f
#define MP 100096        // NN padded to multiple of 128
#define MBLK (MP / 128)  // 782
#define NB 782           // buckets of 128 dest nodes
#define CAP 2560         // bucket entry capacity (mean 2046, sd ~45)
#define CAPP 3584        // per-bucket srcs region (CAP + 128*8 pad room)

typedef unsigned short u16;
typedef __attribute__((ext_vector_type(8))) short short8;
typedef __attribute__((ext_vector_type(4))) float f32x4;

struct alignas(4)  u16x2 { u16 v[2]; };
struct alignas(8)  u16x4 { u16 v[4]; };
struct alignas(16) u16x8 { u16 v[8]; };

__device__ __forceinline__ float b2f(u16 u) { return __uint_as_float(((unsigned)u) << 16); }
__device__ __forceinline__ u16 f2b(float f) {
    unsigned u = __float_as_uint(f);
    return (u16)((u + 0x7FFF + ((u >> 16) & 1)) >> 16);
}
__device__ __forceinline__ void gload16(const void* g, void* l) {
    __builtin_amdgcn_global_load_lds((const __attribute__((address_space(1))) void*)g,
                                     (__attribute__((address_space(3))) void*)l, 16, 0, 0);
}

// ---------------- initcast: x-cast + 3 weight-casts + all zero-fills, ONE dispatch ----------------
// thread ranges: [0, NN*32) xcast | +131072 wcasts | + ZB4 zero fills

#define ZB0 (NB * 16)
#define ZB1 (ZB0 + 1280)
#define ZB2 (ZB1 + 1)
#define ZB3 (ZB2 + (MP - NN) * 64)    // bufA pad rows, 128-wide layout (u32 units)
#define ZB4 (ZB3 + (MP - NN) * 128)   // bufA pad rows, 256-wide layout
#define ICTOT (NN * 32 + 131072 + ZB4)

__global__ void initcast_kernel(const float* __restrict__ x, u16* __restrict__ xb,
                                const float* __restrict__ W1, const float* __restrict__ W2,
                                const float* __restrict__ W3, u16* __restrict__ Wt1,
                                u16* __restrict__ Wt2, u16* __restrict__ Wt3,
                                unsigned* __restrict__ bcur, unsigned* __restrict__ statsAll,
                                unsigned* __restrict__ dinvNN, unsigned* __restrict__ padA128,
                                unsigned* __restrict__ padA256) {
    int idx = blockIdx.x * 256 + threadIdx.x;
    if (idx < NN * 32) {
        float4 v = ((const float4*)x)[idx];
        u16x4 o = {{f2b(v.x), f2b(v.y), f2b(v.z), f2b(v.w)}};
        ((u16x4*)xb)[idx] = o;
        return;
    }
    int j = idx - NN * 32;
    if (j < 32768) {                  // Wt1[n*128+k] = W1[k*256+n]
        int n = j >> 7, k = j & 127;
        Wt1[j] = f2b(W1[k * 256 + n]);
        return;
    }
    if (j < 98304) {                  // Wt2[n*256+k] = W2[k*256+n]
        int jj = j - 32768;
        int n = jj >> 8, k = jj & 255;
        Wt2[jj] = f2b(W2[k * 256 + n]);
        return;
    }
    if (j < 131072) {                 // Wt3[n*256+k] = W3[k*128+n]
        int jj = j - 98304;
        int n = jj >> 8, k = jj & 255;
        Wt3[jj] = f2b(W3[k * 128 + n]);
        return;
    }
    int z = j - 131072;
    if (z < ZB0) bcur[z] = 0u;
    else if (z < ZB1) statsAll[z - ZB0] = 0u;
    else if (z < ZB2) dinvNN[0] = 0u;
    else if (z < ZB3) padA128[z - ZB2] = 0u;
    else if (z < ZB4) padA256[z - ZB3] = 0u;
}

// ---------------- CSR build (bucketed, fixed-stride regions) ----------------

__global__ void bucketA_kernel(const int* __restrict__ row, const int* __restrict__ col,
                               int* __restrict__ bcur, unsigned* __restrict__ bkt) {
    int e = blockIdx.x * 256 + threadIdx.x;
    if (e < EE) {
        int c = col[e], r = row[e];
        int b = c >> 7;
        int p = atomicAdd(&bcur[b * 16], 1);
        if (p < CAP) bkt[(size_t)b * CAP + p] = ((unsigned)r << 7) | (unsigned)(c & 127);
    }
}

__global__ void bucketBC_kernel(const unsigned* __restrict__ bkt, const int* __restrict__ bcur,
                                int* __restrict__ begs, int* __restrict__ ends,
                                float* __restrict__ dinv, int* __restrict__ srcs) {
    int b = blockIdx.x, t = threadIdx.x;   // 256 threads
    __shared__ int lcnt[128];
    __shared__ int sp[128];
    __shared__ int cur[128];
    if (t < 128) lcnt[t] = 0;
    __syncthreads();
    int tot = bcur[b * 16];
    if (tot > CAP) tot = CAP;
    const unsigned* B = bkt + (size_t)b * CAP;
    for (int i = t; i < tot; i += 256) atomicAdd(&lcnt[(int)(B[i] & 127u)], 1);
    __syncthreads();
    int n0 = b << 7;
    int pc = 0;
    if (t < 128) {
        int rc = lcnt[t];
        if (n0 + t < NN) dinv[n0 + t] = rsqrtf((float)(rc + 1));
        pc = (rc + 7) & ~7;
        sp[t] = pc;
    }
    __syncthreads();
    for (int o = 1; o < 128; o <<= 1) {
        int u = (t >= o && t < 128) ? sp[t - o] : 0;
        __syncthreads();
        if (t < 128) sp[t] += u;
        __syncthreads();
    }
    int base = b * CAPP;
    if (t < 128) {
        int st = base + sp[t] - pc;
        cur[t] = st;
        if (n0 + t < NN) { begs[n0 + t] = st; ends[n0 + t] = st + pc; }
    }
    __syncthreads();
    for (int i = t; i < tot; i += 256) {
        unsigned v = B[i];
        int p = atomicAdd(&cur[(int)(v & 127u)], 1);
        srcs[p] = (int)(v >> 7);
    }
    __syncthreads();
    if (t < 128 && n0 + t < NN) {
        int st = cur[t];              // begs + real count
        int en = base + sp[t];        // begs + padded count
        for (int i = st; i < en; ++i) srcs[i] = NN;   // dummy: dinv[NN]=0
    }
}

// ---------------- aggregation (r8-proven: one node per 64-lane wave; lists padded x8) ----------------
// out[i] = dinv[i] * ( sum_e dinv[src_e]*f(X[src_e]) + dinv[i]*f(X[i]) ); f = id or relu(s*z+t)

template <int F, bool TR>
__global__ void agg_kernel(const u16* __restrict__ X, u16* __restrict__ out,
                           const int* __restrict__ begs, const int* __restrict__ ends,
                           const int* __restrict__ srcs, const float* __restrict__ dinv,
                           const float* __restrict__ sc, const float* __restrict__ shf) {
    constexpr int VE = F / 64;   // 4 (F=256) or 2 (F=128)
    int node = blockIdx.x * 4 + (threadIdx.x >> 6);
    if (node >= NN) return;
    int l = threadIdx.x & 63;
    int f0 = l * VE;
    float s_[VE], t_[VE];
    if (TR) {
#pragma unroll
        for (int j = 0; j < VE; ++j) { s_[j] = sc[f0 + j]; t_[j] = shf[f0 + j]; }
    }
    float acc[VE] = {};
    int beg = begs[node], end = ends[node];

    auto fetch = [&](int s, u16* u) {
        if (VE == 4) *(u16x4*)u = *(const u16x4*)(X + (size_t)s * F + f0);
        else         *(u16x2*)u = *(const u16x2*)(X + (size_t)s * F + f0);
    };
    auto accum = [&](const u16* u, float w) {
#pragma unroll
        for (int j = 0; j < VE; ++j) {
            float v = b2f(u[j]);
            if (TR) v = fmaxf(fmaf(s_[j], v, t_[j]), 0.f);
            acc[j] = fmaf(w, v, acc[j]);
        }
    };

    for (int e0 = beg; e0 < end; e0 += 64) {
        int take = end - e0;
        if (take > 64) take = 64;      // always a multiple of 8
        int sv = (l < take) ? srcs[e0 + l] : NN;
        float wv = dinv[sv];
        for (int j = 0; j < take; j += 8) {
            int s[8];
            float w[8];
            u16 u[8][VE];
#pragma unroll
            for (int q = 0; q < 8; ++q) {
                s[q] = __shfl(sv, j + q);
                w[q] = __shfl(wv, j + q);
            }
#pragma unroll
            for (int q = 0; q < 8; ++q) fetch(s[q], u[q]);
#pragma unroll
            for (int q = 0; q < 8; ++q) accum(u[q], w[q]);
        }
    }
    float di = dinv[node];
    u16 us[VE];
    fetch(node, us);
    accum(us, di);
    if (VE == 4) {
        u16x4 o = {{f2b(di * acc[0]), f2b(di * acc[1]), f2b(di * acc[2]), f2b(di * acc[3])}};
        *(u16x4*)(out + (size_t)node * F + f0) = o;
    } else {
        u16x2 o = {{f2b(di * acc[0]), f2b(di * acc[1])}};
        *(u16x2*)(out + (size_t)node * F + f0) = o;
    }
}

// ---------------- MFMA GEMM: C[MP,Nout](bf16) = f(A[MP,Kdim]) @ Wt[Nout,Kdim]^T ----------------
// STATS: LDS-reduce column (sum,sumsq) partials, then 256 atomicAdds into gstats[2*Nout].

template <bool STATS, bool FUSEA>
__global__ __launch_bounds__(256) void gemm_kernel(const u16* __restrict__ A,
                                                   const u16* __restrict__ Wt,
                                                   u16* __restrict__ C,
                                                   int Kdim, int Nout,
                                                   float* __restrict__ gstats,
                                                   const float* __restrict__ sc,
                                                   const float* __restrict__ shf) {
    __shared__ u16 As[128 * 64];
    __shared__ u16 Bs[128 * 64];
    __shared__ float sbuf[2][128];
    const int tid = threadIdx.x;
    const int w = tid >> 6, l = tid & 63;
    const int row0 = blockIdx.x * 128;
    const int col0 = blockIdx.y * 128;
    const int srow = w * 32 + (l >> 3);
    const int skel = (l & 7) * 8;
    const u16* Asrc = A + (size_t)(row0 + srow) * Kdim + skel;
    const u16* Bsrc = Wt + (size_t)(col0 + srow) * Kdim + skel;
    u16* AsBase = &As[w * 2048];
    u16* BsBase = &Bs[w * 2048];
    const int wr = (w >> 1) * 64, wc = (w & 1) * 64;
    f32x4 acc[4][4] = {};
    if (STATS && tid < 128) { sbuf[0][tid] = 0.f; sbuf[1][tid] = 0.f; }

    for (int k0 = 0; k0 < Kdim; k0 += 64) {
        if (FUSEA) {
            float4 sa0 = *(const float4*)&sc[k0 + skel];
            float4 sa1 = *(const float4*)&sc[k0 + skel + 4];
            float4 ta0 = *(const float4*)&shf[k0 + skel];
            float4 ta1 = *(const float4*)&shf[k0 + skel + 4];
            float sA[8] = {sa0.x, sa0.y, sa0.z, sa0.w, sa1.x, sa1.y, sa1.z, sa1.w};
            float tA[8] = {ta0.x, ta0.y, ta0.z, ta0.w, ta1.x, ta1.y, ta1.z, ta1.w};
#pragma unroll
            for (int j = 0; j < 4; ++j) {
                u16x8 av = *(const u16x8*)(Asrc + (size_t)(j * 8) * Kdim + k0);
                u16x8 o;
#pragma unroll
                for (int i = 0; i < 8; ++i)
                    o.v[i] = f2b(fmaxf(fmaf(sA[i], b2f(av.v[i]), tA[i]), 0.f));
                *(u16x8*)&As[(w * 32 + j * 8 + (l >> 3)) * 64 + skel] = o;
            }
        } else {
#pragma unroll
            for (int j = 0; j < 4; ++j)
                gload16(Asrc + (size_t)(j * 8) * Kdim + k0, AsBase + j * 512);
        }
#pragma unroll
        for (int j = 0; j < 4; ++j)
            gload16(Bsrc + (size_t)(j * 8) * Kdim + k0, BsBase + j * 512);
        __syncthreads();
#pragma unroll
        for (int ks = 0; ks < 2; ++ks) {
            short8 a[4], b[4];
#pragma unroll
            for (int mi = 0; mi < 4; ++mi)
                a[mi] = *(const short8*)&As[(wr + mi * 16 + (l & 15)) * 64 + ks * 32 + (l >> 4) * 8];
#pragma unroll
            for (int ni = 0; ni < 4; ++ni)
                b[ni] = *(const short8*)&Bs[(wc + ni * 16 + (l & 15)) * 64 + ks * 32 + (l >> 4) * 8];
#pragma unroll
            for (int mi = 0; mi < 4; ++mi)
#pragma unroll
                for (int ni = 0; ni < 4; ++ni)
                    acc[mi][ni] = __builtin_amdgcn_mfma_f32_16x16x32_bf16(a[mi], b[ni], acc[mi][ni], 0, 0, 0);
        }
        __syncthreads();
    }
    const int cr = (l >> 4) * 4, cc = l & 15;
#pragma unroll
    for (int mi = 0; mi < 4; ++mi) {
#pragma unroll
        for (int j = 0; j < 4; ++j) {
            int r = row0 + wr + mi * 16 + cr + j;
#pragma unroll
            for (int ni = 0; ni < 4; ++ni)
                C[(size_t)r * Nout + col0 + wc + ni * 16 + cc] = f2b(acc[mi][ni][j]);
        }
    }
    if (STATS) {
#pragma unroll
        for (int ni = 0; ni < 4; ++ni) {
            float s = 0.f, q = 0.f;
#pragma unroll
            for (int mi = 0; mi < 4; ++mi)
#pragma unroll
                for (int jj = 0; jj < 4; ++jj) {
                    float v = acc[mi][ni][jj];
                    s += v;
                    q += v * v;
                }
            s += __shfl_xor(s, 16); s += __shfl_xor(s, 32);
            q += __shfl_xor(q, 16); q += __shfl_xor(q, 32);
            if (l < 16) {
                atomicAdd(&sbuf[0][wc + ni * 16 + l], s);
                atomicAdd(&sbuf[1][wc + ni * 16 + l], q);
            }
        }
        __syncthreads();
        if (tid < 128) {
            atomicAdd(&gstats[col0 + tid], sbuf[0][tid]);
            atomicAdd(&gstats[Nout + col0 + tid], sbuf[1][tid]);
        }
    }
}

// ---------------- finalize (tiny): sums[2F] -> scale/shift ----------------

__global__ void finalize_kernel(const float* __restrict__ sums, int F,
                                const float* __restrict__ g, const float* __restrict__ be,
                                float* __restrict__ sc, float* __restrict__ shf) {
    int f = threadIdx.x;
    if (f < F) {
        float m = sums[f] * (1.f / NN);
        float v = sums[F + f] * (1.f / NN) - m * m;
        float s = g[f] * rsqrtf(v + EPSB);
        sc[f] = s;
        shf[f] = be[f] - m * s;
    }
}

// ---------------- fused layer-3 stats + pool ----------------

__global__ void poolstats_kernel(const u16* __restrict__ Z, const int* __restrict__ batch,
                                 float* __restrict__ gsum, int* __restrict__ gcnt,
                                 float* __restrict__ sums) {
    int gph = blockIdx.x;
    int f = threadIdx.x;   // 128
    __shared__ int sb, se;
    if (f == 0) {
        int lo = 0, hi = NN;
        while (lo < hi) { int mid = (lo + hi) >> 1; if (batch[mid] < gph) lo = mid + 1; else hi = mid; }
        sb = lo;
        hi = NN;
        while (lo < hi) { int mid = (lo + hi) >> 1; if (batch[mid] < gph + 1) lo = mid + 1; else hi = mid; }
        se = lo;
    }
    __syncthreads();
    int beg = sb, end = se;
    float acc = 0.f, qq = 0.f;
    for (int r = beg; r < end; ++r) {
        float v = b2f(Z[(size_t)r * 128 + f]);
        acc += v;
        qq += v * v;
    }
    gsum[(size_t)gph * 128 + f] = acc;
    if (f == 0) gcnt[gph] = end - beg;
    atomicAdd(&sums[f], acc);
    atomicAdd(&sums[128 + f], qq);
}

// poolout with fused layer-3 finalize (recompute per thread from the tiny stats buffer)
__global__ void poolout_kernel(const float* __restrict__ gsum, const int* __restrict__ gcnt,
                               const float* __restrict__ sums,
                               const float* __restrict__ g, const float* __restrict__ be,
                               float* __restrict__ out) {
    int i = blockIdx.x * 256 + threadIdx.x;
    if (i < GG * 128) {
        int gr = i >> 7, f = i & 127;
        float m = sums[f] * (1.f / NN);
        float v = sums[128 + f] * (1.f / NN) - m * m;
        float scv = g[f] * rsqrtf(v + EPSB);
        float shv = be[f] - m * scv;
        int c = gcnt[gr];
        out[i] = (c > 0) ? fmaf(scv, gsum[i] / (float)c, shv) : 0.f;
    }
}

// ---------------- launch ----------------

extern "C" void kernel_launch(void* const* d_in, const int* in_sizes, int n_in,
                              void* d_out, int out_size, void* d_ws, size_t ws_size,
                              hipStream_t stream) {
    const float* x     = (const float*)d_in[0];
    const int*   row   = (const int*)d_in[1];
    const int*   col   = (const int*)d_in[2];
    const int*   batch = (const int*)d_in[3];
    const float* W1 = (const float*)d_in[4];
    const float* g1 = (const float*)d_in[6];
    const float* be1 = (const float*)d_in[7];
    const float* W2 = (const float*)d_in[8];
    const float* g2 = (const float*)d_in[10];
    const float* be2 = (const float*)d_in[11];
    const float* W3 = (const float*)d_in[12];
    const float* g3 = (const float*)d_in[14];
    const float* be3 = (const float*)d_in[15];
    float* out = (float*)d_out;

    char* ws = (char*)d_ws;
    size_t off = 0;
    auto alloc = [&](size_t bytes) { size_t o = off; off += (bytes + 255) & ~255ULL; return o; };
    u16*   bufA   = (u16*)  (ws + alloc((size_t)MP * 256 * 2));   // T1 / T2 / H3
    u16*   bufB   = (u16*)  (ws + alloc((size_t)MP * 256 * 2));   // Z1 / Z2
    u16*   xb     = (u16*)  (ws + alloc((size_t)MP * 128 * 2));   // x bf16, later Z3
    u16*   Wt1    = (u16*)  (ws + alloc(128 * 256 * 2));
    u16*   Wt2    = (u16*)  (ws + alloc(256 * 256 * 2));
    u16*   Wt3    = (u16*)  (ws + alloc(256 * 128 * 2));
    int*   begs   = (int*)  (ws + alloc((size_t)(NN + 16) * 4));
    int*   ends   = (int*)  (ws + alloc((size_t)(NN + 16) * 4));
    float* dinv   = (float*)(ws + alloc((size_t)(NN + 16) * 4));
    int*   srcs   = (int*)  (ws + alloc((size_t)NB * CAPP * 4));
    unsigned* bkt = (unsigned*)(ws + alloc((size_t)NB * CAP * 4));
    int*   bcur   = (int*)  (ws + alloc((size_t)NB * 16 * 4));
    float* statsAll = (float*)(ws + alloc(1280 * 4));   // l1[512] | l2[512] | p3[256]
    float* scbuf  = (float*)(ws + alloc(6 * 256 * 4));
    float* gsum   = (float*)(ws + alloc((size_t)GG * 128 * 4));
    int*   gcnt   = (int*)  (ws + alloc((size_t)GG * 4));

    // one fused dispatch: x-cast + weight-casts + all zero-fills (replay-safe)
    initcast_kernel<<<(ICTOT + 255) / 256, 256, 0, stream>>>(
        x, xb, W1, W2, W3, Wt1, Wt2, Wt3,
        (unsigned*)bcur, (unsigned*)statsAll, (unsigned*)&dinv[NN],
        (unsigned*)(bufA + (size_t)NN * 128), (unsigned*)(bufA + (size_t)NN * 256));

    bucketA_kernel<<<(EE + 255) / 256, 256, 0, stream>>>(row, col, bcur, bkt);
    bucketBC_kernel<<<NB, 256, 0, stream>>>(bkt, bcur, begs, ends, dinv, srcs);

    const int aggBlocks = (NN + 3) / 4;

    // Layer 1: T1 = S@xb, Z1 = T1@W1 (stats via fused atomics)
    agg_kernel<128, false><<<aggBlocks, 256, 0, stream>>>(xb, bufA, begs, ends, srcs, dinv, nullptr, nullptr);
    gemm_kernel<true, false><<<dim3(MBLK, 2), 256, 0, stream>>>(bufA, Wt1, bufB, 128, 256, statsAll, nullptr, nullptr);
    finalize_kernel<<<1, 256, 0, stream>>>(statsAll, 256, g1, be1, scbuf + 0, scbuf + 256);

    // Layer 2: T2 = S@relu(bn1(Z1)) (BN fused in gather), Z2 = T2@W2 (stats via fused atomics)
    agg_kernel<256, true><<<aggBlocks, 256, 0, stream>>>(bufB, bufA, begs, ends, srcs, dinv, scbuf + 0, scbuf + 256);
    gemm_kernel<true, false><<<dim3(MBLK, 2), 256, 0, stream>>>(bufA, Wt2, bufB, 256, 256, statsAll + 512, nullptr, nullptr);
    finalize_kernel<<<1, 256, 0, stream>>>(statsAll + 512, 256, g2, be2, scbuf + 512, scbuf + 768);

    // Layer 3: H3 = relu(bn2(Z2))@W3 (BN fused in A-staging), Z3 = S@H3
    gemm_kernel<false, true><<<dim3(MBLK, 1), 256, 0, stream>>>(bufB, Wt3, bufA, 256, 128, nullptr, scbuf + 512, scbuf + 768);
    agg_kernel<128, false><<<aggBlocks, 256, 0, stream>>>(bufA, xb, begs, ends, srcs, dinv, nullptr, nullptr);
    poolstats_kernel<<<GG, 128, 0, stream>>>(xb, batch, gsum, gcnt, statsAll + 1024);
    poolout_kernel<<<(GG * 128 + 255) / 256, 256, 0, stream>>>(gsum, gcnt, statsAll + 1024, g3, be3, out);
}

// Round 11
// 555.703 us; speedup vs baseline: 1.0695x; 1.0040x over previous
//
#include <hip/hip_runtime.h>

#define NN 100000
#define EE 1600000
#define GG 2048
#define EPSB 1e-5f
#define MP 100096        // NN padded to multiple of 128
#define MBLK (MP / 128)  // 782
#define NB 782           // buckets of 128 dest nodes
#define CAP 2560         // bucket entry capacity (mean 2046, sd ~45)
#define CAPP 3584        // per-bucket srcs region (CAP + 128*8 pad room)

typedef unsigned short u16;
typedef __attribute__((ext_vector_type(8))) short short8;
typedef __attribute__((ext_vector_type(4))) float f32x4;

struct alignas(4)  u16x2 { u16 v[2]; };
struct alignas(8)  u16x4 { u16 v[4]; };
struct alignas(16) u16x8 { u16 v[8]; };

__device__ __forceinline__ float b2f(u16 u) { return __uint_as_float(((unsigned)u) << 16); }
__device__ __forceinline__ u16 f2b(float f) {
    unsigned u = __float_as_uint(f);
    return (u16)((u + 0x7FFF + ((u >> 16) & 1)) >> 16);
}
__device__ __forceinline__ void gload16(const void* g, void* l) {
    __builtin_amdgcn_global_load_lds((const __attribute__((address_space(1))) void*)g,
                                     (__attribute__((address_space(3))) void*)l, 16, 0, 0);
}
// BN affine from raw sums: sc = g*rsqrt(var+eps), shf = be - mean*sc
__device__ __forceinline__ void bnaffine(const float* __restrict__ sums, int F, int f,
                                         const float* __restrict__ g, const float* __restrict__ be,
                                         float& sc, float& shf) {
    float m = sums[f] * (1.f / NN);
    float v = sums[F + f] * (1.f / NN) - m * m;
    sc = g[f] * rsqrtf(v + EPSB);
    shf = be[f] - m * sc;
}

// ---------------- initcast: x-cast + 3 weight-casts + all zero-fills, ONE dispatch ----------------

#define ZB0 (NB * 16)
#define ZB1 (ZB0 + 1280)
#define ZB2 (ZB1 + 1)
#define ZB3 (ZB2 + (MP - NN) * 64)    // bufA pad rows, 128-wide layout (u32 units)
#define ZB4 (ZB3 + (MP - NN) * 128)   // bufA pad rows, 256-wide layout
#define ICTOT (NN * 32 + 131072 + ZB4)

__global__ void initcast_kernel(const float* __restrict__ x, u16* __restrict__ xb,
                                const float* __restrict__ W1, const float* __restrict__ W2,
                                const float* __restrict__ W3, u16* __restrict__ Wt1,
                                u16* __restrict__ Wt2, u16* __restrict__ Wt3,
                                unsigned* __restrict__ bcur, unsigned* __restrict__ statsAll,
                                unsigned* __restrict__ dinvNN, unsigned* __restrict__ padA128,
                                unsigned* __restrict__ padA256) {
    int idx = blockIdx.x * 256 + threadIdx.x;
    if (idx < NN * 32) {
        float4 v = ((const float4*)x)[idx];
        u16x4 o = {{f2b(v.x), f2b(v.y), f2b(v.z), f2b(v.w)}};
        ((u16x4*)xb)[idx] = o;
        return;
    }
    int j = idx - NN * 32;
    if (j < 32768) {                  // Wt1[n*128+k] = W1[k*256+n]
        int n = j >> 7, k = j & 127;
        Wt1[j] = f2b(W1[k * 256 + n]);
        return;
    }
    if (j < 98304) {                  // Wt2[n*256+k] = W2[k*256+n]
        int jj = j - 32768;
        int n = jj >> 8, k = jj & 255;
        Wt2[jj] = f2b(W2[k * 256 + n]);
        return;
    }
    if (j < 131072) {                 // Wt3[n*256+k] = W3[k*128+n]
        int jj = j - 98304;
        int n = jj >> 8, k = jj & 255;
        Wt3[jj] = f2b(W3[k * 128 + n]);
        return;
    }
    int z = j - 131072;
    if (z < ZB0) bcur[z] = 0u;
    else if (z < ZB1) statsAll[z - ZB0] = 0u;
    else if (z < ZB2) dinvNN[0] = 0u;
    else if (z < ZB3) padA128[z - ZB2] = 0u;
    else if (z < ZB4) padA256[z - ZB3] = 0u;
}

// ---------------- CSR build (bucketed, fixed-stride regions) ----------------

__global__ void bucketA_kernel(const int* __restrict__ row, const int* __restrict__ col,
                               int* __restrict__ bcur, unsigned* __restrict__ bkt) {
    int e = blockIdx.x * 256 + threadIdx.x;
    if (e < EE) {
        int c = col[e], r = row[e];
        int b = c >> 7;
        int p = atomicAdd(&bcur[b * 16], 1);
        if (p < CAP) bkt[(size_t)b * CAP + p] = ((unsigned)r << 7) | (unsigned)(c & 127);
    }
}

__global__ void bucketBC_kernel(const unsigned* __restrict__ bkt, const int* __restrict__ bcur,
                                int* __restrict__ begs, int* __restrict__ ends,
                                float* __restrict__ dinv, int* __restrict__ srcs) {
    int b = blockIdx.x, t = threadIdx.x;   // 256 threads
    __shared__ int lcnt[128];
    __shared__ int sp[128];
    __shared__ int cur[128];
    if (t < 128) lcnt[t] = 0;
    __syncthreads();
    int tot = bcur[b * 16];
    if (tot > CAP) tot = CAP;
    const unsigned* B = bkt + (size_t)b * CAP;
    for (int i = t; i < tot; i += 256) atomicAdd(&lcnt[(int)(B[i] & 127u)], 1);
    __syncthreads();
    int n0 = b << 7;
    int pc = 0;
    if (t < 128) {
        int rc = lcnt[t];
        if (n0 + t < NN) dinv[n0 + t] = rsqrtf((float)(rc + 1));
        pc = (rc + 7) & ~7;
        sp[t] = pc;
    }
    __syncthreads();
    for (int o = 1; o < 128; o <<= 1) {
        int u = (t >= o && t < 128) ? sp[t - o] : 0;
        __syncthreads();
        if (t < 128) sp[t] += u;
        __syncthreads();
    }
    int base = b * CAPP;
    if (t < 128) {
        int st = base + sp[t] - pc;
        cur[t] = st;
        if (n0 + t < NN) { begs[n0 + t] = st; ends[n0 + t] = st + pc; }
    }
    __syncthreads();
    for (int i = t; i < tot; i += 256) {
        unsigned v = B[i];
        int p = atomicAdd(&cur[(int)(v & 127u)], 1);
        srcs[p] = (int)(v >> 7);
    }
    __syncthreads();
    if (t < 128 && n0 + t < NN) {
        int st = cur[t];              // begs + real count
        int en = base + sp[t];        // begs + padded count
        for (int i = st; i < en; ++i) srcs[i] = NN;   // dummy: dinv[NN]=0
    }
}

// ---------------- aggregation (one node per 64-lane wave; lists padded x8) ----------------
// out[i] = dinv[i] * ( sum_e dinv[src_e]*f(X[src_e]) + dinv[i]*f(X[i]) )
// TR: f = relu(sc*z+shf) with affine derived IN-KERNEL from raw sums (finalize fused)

template <int F, bool TR>
__global__ void agg_kernel(const u16* __restrict__ X, u16* __restrict__ out,
                           const int* __restrict__ begs, const int* __restrict__ ends,
                           const int* __restrict__ srcs, const float* __restrict__ dinv,
                           const float* __restrict__ sums, const float* __restrict__ g,
                           const float* __restrict__ be) {
    constexpr int VE = F / 64;   // 4 (F=256) or 2 (F=128)
    int node = blockIdx.x * 4 + (threadIdx.x >> 6);
    if (node >= NN) return;
    int l = threadIdx.x & 63;
    int f0 = l * VE;
    float s_[VE], t_[VE];
    if (TR) {
#pragma unroll
        for (int j = 0; j < VE; ++j) bnaffine(sums, F, f0 + j, g, be, s_[j], t_[j]);
    }
    float acc[VE] = {};
    int beg = begs[node], end = ends[node];

    auto fetch = [&](int s, u16* u) {
        if (VE == 4) *(u16x4*)u = *(const u16x4*)(X + (size_t)s * F + f0);
        else         *(u16x2*)u = *(const u16x2*)(X + (size_t)s * F + f0);
    };
    auto accum = [&](const u16* u, float w) {
#pragma unroll
        for (int j = 0; j < VE; ++j) {
            float v = b2f(u[j]);
            if (TR) v = fmaxf(fmaf(s_[j], v, t_[j]), 0.f);
            acc[j] = fmaf(w, v, acc[j]);
        }
    };

    for (int e0 = beg; e0 < end; e0 += 64) {
        int take = end - e0;
        if (take > 64) take = 64;      // always a multiple of 8
        int sv = (l < take) ? srcs[e0 + l] : NN;
        float wv = dinv[sv];
        for (int j = 0; j < take; j += 8) {
            int s[8];
            float w[8];
            u16 u[8][VE];
#pragma unroll
            for (int q = 0; q < 8; ++q) {
                s[q] = __shfl(sv, j + q);
                w[q] = __shfl(wv, j + q);
            }
#pragma unroll
            for (int q = 0; q < 8; ++q) fetch(s[q], u[q]);
#pragma unroll
            for (int q = 0; q < 8; ++q) accum(u[q], w[q]);
        }
    }
    float di = dinv[node];
    u16 us[VE];
    fetch(node, us);
    accum(us, di);
    if (VE == 4) {
        u16x4 o = {{f2b(di * acc[0]), f2b(di * acc[1]), f2b(di * acc[2]), f2b(di * acc[3])}};
        *(u16x4*)(out + (size_t)node * F + f0) = o;
    } else {
        u16x2 o = {{f2b(di * acc[0]), f2b(di * acc[1])}};
        *(u16x2*)(out + (size_t)node * F + f0) = o;
    }
}

// ---------------- MFMA GEMM: C[MP,Nout](bf16) = f(A[MP,Kdim]) @ Wt[Nout,Kdim]^T ----------------
// STATS: LDS-reduce column (sum,sumsq) partials, then 256 atomicAdds into gstats[2*Nout].
// FUSEA: relu(sc*a+shf) applied during A-staging, affine derived IN-KERNEL from raw sums.

template <bool STATS, bool FUSEA>
__global__ __launch_bounds__(256) void gemm_kernel(const u16* __restrict__ A,
                                                   const u16* __restrict__ Wt,
                                                   u16* __restrict__ C,
                                                   int Kdim, int Nout,
                                                   float* __restrict__ gstats,
                                                   const float* __restrict__ sums,
                                                   const float* __restrict__ g,
                                                   const float* __restrict__ be) {
    __shared__ u16 As[128 * 64];
    __shared__ u16 Bs[128 * 64];
    __shared__ float sbuf[2][128];
    const int tid = threadIdx.x;
    const int w = tid >> 6, l = tid & 63;
    const int row0 = blockIdx.x * 128;
    const int col0 = blockIdx.y * 128;
    const int srow = w * 32 + (l >> 3);
    const int skel = (l & 7) * 8;
    const u16* Asrc = A + (size_t)(row0 + srow) * Kdim + skel;
    const u16* Bsrc = Wt + (size_t)(col0 + srow) * Kdim + skel;
    u16* AsBase = &As[w * 2048];
    u16* BsBase = &Bs[w * 2048];
    const int wr = (w >> 1) * 64, wc = (w & 1) * 64;
    f32x4 acc[4][4] = {};
    if (STATS && tid < 128) { sbuf[0][tid] = 0.f; sbuf[1][tid] = 0.f; }

    for (int k0 = 0; k0 < Kdim; k0 += 64) {
        if (FUSEA) {
            float sA[8], tA[8];
#pragma unroll
            for (int i = 0; i < 8; ++i) bnaffine(sums, 256, k0 + skel + i, g, be, sA[i], tA[i]);
#pragma unroll
            for (int j = 0; j < 4; ++j) {
                u16x8 av = *(const u16x8*)(Asrc + (size_t)(j * 8) * Kdim + k0);
                u16x8 o;
#pragma unroll
                for (int i = 0; i < 8; ++i)
                    o.v[i] = f2b(fmaxf(fmaf(sA[i], b2f(av.v[i]), tA[i]), 0.f));
                *(u16x8*)&As[(w * 32 + j * 8 + (l >> 3)) * 64 + skel] = o;
            }
        } else {
#pragma unroll
            for (int j = 0; j < 4; ++j)
                gload16(Asrc + (size_t)(j * 8) * Kdim + k0, AsBase + j * 512);
        }
#pragma unroll
        for (int j = 0; j < 4; ++j)
            gload16(Bsrc + (size_t)(j * 8) * Kdim + k0, BsBase + j * 512);
        __syncthreads();
#pragma unroll
        for (int ks = 0; ks < 2; ++ks) {
            short8 a[4], b[4];
#pragma unroll
            for (int mi = 0; mi < 4; ++mi)
                a[mi] = *(const short8*)&As[(wr + mi * 16 + (l & 15)) * 64 + ks * 32 + (l >> 4) * 8];
#pragma unroll
            for (int ni = 0; ni < 4; ++ni)
                b[ni] = *(const short8*)&Bs[(wc + ni * 16 + (l & 15)) * 64 + ks * 32 + (l >> 4) * 8];
#pragma unroll
            for (int mi = 0; mi < 4; ++mi)
#pragma unroll
                for (int ni = 0; ni < 4; ++ni)
                    acc[mi][ni] = __builtin_amdgcn_mfma_f32_16x16x32_bf16(a[mi], b[ni], acc[mi][ni], 0, 0, 0);
        }
        __syncthreads();
    }
    const int cr = (l >> 4) * 4, cc = l & 15;
#pragma unroll
    for (int mi = 0; mi < 4; ++mi) {
#pragma unroll
        for (int j = 0; j < 4; ++j) {
            int r = row0 + wr + mi * 16 + cr + j;
#pragma unroll
            for (int ni = 0; ni < 4; ++ni)
                C[(size_t)r * Nout + col0 + wc + ni * 16 + cc] = f2b(acc[mi][ni][j]);
        }
    }
    if (STATS) {
#pragma unroll
        for (int ni = 0; ni < 4; ++ni) {
            float s = 0.f, q = 0.f;
#pragma unroll
            for (int mi = 0; mi < 4; ++mi)
#pragma unroll
                for (int jj = 0; jj < 4; ++jj) {
                    float v = acc[mi][ni][jj];
                    s += v;
                    q += v * v;
                }
            s += __shfl_xor(s, 16); s += __shfl_xor(s, 32);
            q += __shfl_xor(q, 16); q += __shfl_xor(q, 32);
            if (l < 16) {
                atomicAdd(&sbuf[0][wc + ni * 16 + l], s);
                atomicAdd(&sbuf[1][wc + ni * 16 + l], q);
            }
        }
        __syncthreads();
        if (tid < 128) {
            atomicAdd(&gstats[col0 + tid], sbuf[0][tid]);
            atomicAdd(&gstats[Nout + col0 + tid], sbuf[1][tid]);
        }
    }
}

// ---------------- fused layer-3 stats + pool ----------------

__global__ void poolstats_kernel(const u16* __restrict__ Z, const int* __restrict__ batch,
                                 float* __restrict__ gsum, int* __restrict__ gcnt,
                                 float* __restrict__ sums) {
    int gph = blockIdx.x;
    int f = threadIdx.x;   // 128
    __shared__ int sb, se;
    if (f == 0) {
        int lo = 0, hi = NN;
        while (lo < hi) { int mid = (lo + hi) >> 1; if (batch[mid] < gph) lo = mid + 1; else hi = mid; }
        sb = lo;
        hi = NN;
        while (lo < hi) { int mid = (lo + hi) >> 1; if (batch[mid] < gph + 1) lo = mid + 1; else hi = mid; }
        se = lo;
    }
    __syncthreads();
    int beg = sb, end = se;
    float acc = 0.f, qq = 0.f;
    for (int r = beg; r < end; ++r) {
        float v = b2f(Z[(size_t)r * 128 + f]);
        acc += v;
        qq += v * v;
    }
    gsum[(size_t)gph * 128 + f] = acc;
    if (f == 0) gcnt[gph] = end - beg;
    atomicAdd(&sums[f], acc);
    atomicAdd(&sums[128 + f], qq);
}

// poolout with fused layer-3 finalize
__global__ void poolout_kernel(const float* __restrict__ gsum, const int* __restrict__ gcnt,
                               const float* __restrict__ sums,
                               const float* __restrict__ g, const float* __restrict__ be,
                               float* __restrict__ out) {
    int i = blockIdx.x * 256 + threadIdx.x;
    if (i < GG * 128) {
        int gr = i >> 7, f = i & 127;
        float scv, shv;
        bnaffine(sums, 128, f, g, be, scv, shv);
        int c = gcnt[gr];
        out[i] = (c > 0) ? fmaf(scv, gsum[i] / (float)c, shv) : 0.f;
    }
}

// ---------------- launch ----------------

extern "C" void kernel_launch(void* const* d_in, const int* in_sizes, int n_in,
                              void* d_out, int out_size, void* d_ws, size_t ws_size,
                              hipStream_t stream) {
    const float* x     = (const float*)d_in[0];
    const int*   row   = (const int*)d_in[1];
    const int*   col   = (const int*)d_in[2];
    const int*   batch = (const int*)d_in[3];
    const float* W1 = (const float*)d_in[4];
    const float* g1 = (const float*)d_in[6];
    const float* be1 = (const float*)d_in[7];
    const float* W2 = (const float*)d_in[8];
    const float* g2 = (const float*)d_in[10];
    const float* be2 = (const float*)d_in[11];
    const float* W3 = (const float*)d_in[12];
    const float* g3 = (const float*)d_in[14];
    const float* be3 = (const float*)d_in[15];
    float* out = (float*)d_out;

    char* ws = (char*)d_ws;
    size_t off = 0;
    auto alloc = [&](size_t bytes) { size_t o = off; off += (bytes + 255) & ~255ULL; return o; };
    u16*   bufA   = (u16*)  (ws + alloc((size_t)MP * 256 * 2));   // T1 / T2 / H3
    u16*   bufB   = (u16*)  (ws + alloc((size_t)MP * 256 * 2));   // Z1 / Z2
    u16*   xb     = (u16*)  (ws + alloc((size_t)MP * 128 * 2));   // x bf16, later Z3
    u16*   Wt1    = (u16*)  (ws + alloc(128 * 256 * 2));
    u16*   Wt2    = (u16*)  (ws + alloc(256 * 256 * 2));
    u16*   Wt3    = (u16*)  (ws + alloc(256 * 128 * 2));
    int*   begs   = (int*)  (ws + alloc((size_t)(NN + 16) * 4));
    int*   ends   = (int*)  (ws + alloc((size_t)(NN + 16) * 4));
    float* dinv   = (float*)(ws + alloc((size_t)(NN + 16) * 4));
    int*   srcs   = (int*)  (ws + alloc((size_t)NB * CAPP * 4));
    unsigned* bkt = (unsigned*)(ws + alloc((size_t)NB * CAP * 4));
    int*   bcur   = (int*)  (ws + alloc((size_t)NB * 16 * 4));
    float* statsAll = (float*)(ws + alloc(1280 * 4));   // l1[512] | l2[512] | p3[256]
    float* gsum   = (float*)(ws + alloc((size_t)GG * 128 * 4));
    int*   gcnt   = (int*)  (ws + alloc((size_t)GG * 4));

    // one fused dispatch: x-cast + weight-casts + all zero-fills (replay-safe)
    initcast_kernel<<<(ICTOT + 255) / 256, 256, 0, stream>>>(
        x, xb, W1, W2, W3, Wt1, Wt2, Wt3,
        (unsigned*)bcur, (unsigned*)statsAll, (unsigned*)&dinv[NN],
        (unsigned*)(bufA + (size_t)NN * 128), (unsigned*)(bufA + (size_t)NN * 256));

    bucketA_kernel<<<(EE + 255) / 256, 256, 0, stream>>>(row, col, bcur, bkt);
    bucketBC_kernel<<<NB, 256, 0, stream>>>(bkt, bcur, begs, ends, dinv, srcs);

    const int aggBlocks = (NN + 3) / 4;

    // Layer 1: T1 = S@xb, Z1 = T1@W1 (stats via fused atomics)
    agg_kernel<128, false><<<aggBlocks, 256, 0, stream>>>(xb, bufA, begs, ends, srcs, dinv, nullptr, nullptr, nullptr);
    gemm_kernel<true, false><<<dim3(MBLK, 2), 256, 0, stream>>>(bufA, Wt1, bufB, 128, 256, statsAll, nullptr, nullptr, nullptr);

    // Layer 2: T2 = S@relu(bn1(Z1)) (BN1 finalize+apply fused in gather), Z2 = T2@W2 (stats fused)
    agg_kernel<256, true><<<aggBlocks, 256, 0, stream>>>(bufB, bufA, begs, ends, srcs, dinv, statsAll, g1, be1);
    gemm_kernel<true, false><<<dim3(MBLK, 2), 256, 0, stream>>>(bufA, Wt2, bufB, 256, 256, statsAll + 512, nullptr, nullptr, nullptr);

    // Layer 3: H3 = relu(bn2(Z2))@W3 (BN2 finalize+apply fused in A-staging), Z3 = S@H3
    gemm_kernel<false, true><<<dim3(MBLK, 1), 256, 0, stream>>>(bufB, Wt3, bufA, 256, 128, nullptr, statsAll + 512, g2, be2);
    agg_kernel<128, false><<<aggBlocks, 256, 0, stream>>>(bufA, xb, begs, ends, srcs, dinv, nullptr, nullptr, nullptr);
    poolstats_kernel<<<GG, 128, 0, stream>>>(xb, batch, gsum, gcnt, statsAll + 1024);
    poolout_kernel<<<(GG * 128 + 255) / 256, 256, 0, stream>>>(gsum, gcnt, statsAll + 1024, g3, be3, out);
}